// Round 13
// baseline (170.590 us; speedup 1.0000x reference)
//
#include <hip/hip_runtime.h>
#include <hip/hip_bf16.h>

// Problem: N=10000, E=320000, FIN=512, FH=128, FOUT=40 (derived from in_sizes).
// Padded-CSR pipeline (CAP=128 slots/node), GCN norm factored into GEMM epilogues:
//   out[d] = dinv[d] * ( sum_s H'[s] + H'[d] ),  H' = dinv * (X@W1)   (same layer 2)
//  L1 k_prep       : pack W1(hi/lo) + pack W2(hi/lo, 40->48) + zero cnt/regp
//  L2 k_conv_fill  : [conv] X->bf16   [fill] csr[d*CAP + atomicAdd(cnt[d])] = src
//  L3 k_gemm1_reg  : [gemm] H'(bf16) = dinv * (Xh @ W1), B LDS dbuf, M-tile 32
//                    [reg]  4-lane groups count dst[e] in csr-row src[e]
//  L4 k_agg1_gemm2 : 16 waves/block, wave per node: AGG1row = relu(dinv*(sum H') + b1)
//                    -> LDS (bf16 pairs, stride 68 words); wave 0 then computes
//                    LG'[16 nodes][48] = dinv * (AGG1 @ W2) via 24 MFMAs (fused GEMM2)
//  L5 k_agg2_lsm   : out = log_softmax(dinv[d]*(sum LG') + b2); out[N*F] = reg
// reg identity: reg = sum_{(s,d) in E} A[d,s]; CSR-by-dst row s holds srcs of edges
// into s, so A[d,s] = #occurrences of d in row s.

#define CAP 128

typedef __attribute__((ext_vector_type(8))) short short8;   // 8 x bf16 (4 VGPRs)
typedef __attribute__((ext_vector_type(4))) float float4v;  // MFMA C/D

__device__ __forceinline__ unsigned short f2bf(float f) {
    __hip_bfloat16 b = __float2bfloat16(f);
    return *reinterpret_cast<unsigned short*>(&b);
}
__device__ __forceinline__ float bf2f(unsigned short u) {
    __hip_bfloat16 b = *reinterpret_cast<__hip_bfloat16*>(&u);
    return __bfloat162float(b);
}

// ---- L1: pack W1 hi/lo | pack W2 hi/lo | zero cnt+regp ----
__global__ void k_prep(const float* __restrict__ W1, unsigned short* __restrict__ Bh1,
                       unsigned short* __restrict__ Bl1,
                       const float* __restrict__ W2, unsigned short* __restrict__ Bh2,
                       unsigned short* __restrict__ Bl2,
                       int* __restrict__ zbase, int zints, int p1B, int p2B) {
    int b = blockIdx.x;
    if (b < p1B) {   // pack W1: KB=16, NF=8, N=128
        int t = b * 256 + threadIdx.x;
        int lane = t & 63;
        int f = (t >> 6) % 8;
        int kb = (t >> 6) / 8;
        int kbase = kb * 32 + (lane >> 4) * 8;
        int n = f * 16 + (lane & 15);
        unsigned short hj[8], lj[8];
#pragma unroll
        for (int j = 0; j < 8; j++) {
            float v = W1[(size_t)(kbase + j) * 128 + n];
            unsigned short hb = f2bf(v);
            hj[j] = hb;
            lj[j] = f2bf(v - bf2f(hb));
        }
        ushort4 h0 = {hj[0], hj[1], hj[2], hj[3]}, h1 = {hj[4], hj[5], hj[6], hj[7]};
        ushort4 l0 = {lj[0], lj[1], lj[2], lj[3]}, l1 = {lj[4], lj[5], lj[6], lj[7]};
        ((ushort4*)Bh1)[t * 2] = h0; ((ushort4*)Bh1)[t * 2 + 1] = h1;
        ((ushort4*)Bl1)[t * 2] = l0; ((ushort4*)Bl1)[t * 2 + 1] = l1;
        return;
    }
    b -= p1B;
    if (b < p2B) {   // pack W2: KB=4, NF=3 (48 padded, real N=40)
        int t = b * 256 + threadIdx.x;
        if (t >= 4 * 3 * 64) return;
        int lane = t & 63;
        int f = (t >> 6) % 3;
        int kb = (t >> 6) / 3;
        int kbase = kb * 32 + (lane >> 4) * 8;
        int n = f * 16 + (lane & 15);
        unsigned short hj[8], lj[8];
#pragma unroll
        for (int j = 0; j < 8; j++) {
            float v = (n < 40) ? W2[(size_t)(kbase + j) * 40 + n] : 0.f;
            unsigned short hb = f2bf(v);
            hj[j] = hb;
            lj[j] = f2bf(v - bf2f(hb));
        }
        ushort4 h0 = {hj[0], hj[1], hj[2], hj[3]}, h1 = {hj[4], hj[5], hj[6], hj[7]};
        ushort4 l0 = {lj[0], lj[1], lj[2], lj[3]}, l1 = {lj[4], lj[5], lj[6], lj[7]};
        ((ushort4*)Bh2)[t * 2] = h0; ((ushort4*)Bh2)[t * 2 + 1] = h1;
        ((ushort4*)Bl2)[t * 2] = l0; ((ushort4*)Bl2)[t * 2 + 1] = l1;
        return;
    }
    b -= p2B;
    {   // zero cnt + regp
        int i = b * 256 + threadIdx.x;
        if (i < zints) zbase[i] = 0;
    }
}

// ---- L2: [conv blocks] X->bf16 | [fill blocks] padded-CSR fill (atomic = pos+deg) ----
__global__ void k_conv_fill(const float* __restrict__ x, unsigned short* __restrict__ xh,
                            int total4,
                            const int* __restrict__ src, const int* __restrict__ dst, int E,
                            int* __restrict__ cnt, unsigned short* __restrict__ csr,
                            int convB) {
    if ((int)blockIdx.x < convB) {
        int i = blockIdx.x * 256 + threadIdx.x;
        if (i < total4) {
            float4 v = ((const float4*)x)[i];
            ushort4 h;
            h.x = f2bf(v.x); h.y = f2bf(v.y); h.z = f2bf(v.z); h.w = f2bf(v.w);
            ((ushort4*)xh)[i] = h;
        }
        return;
    }
    int e = ((int)blockIdx.x - convB) * 256 + (int)threadIdx.x;
    if (e >= E) return;
    int d = dst[e];
    int pos = atomicAdd(&cnt[d], 1);
    if (pos < CAP) csr[(size_t)d * CAP + pos] = (unsigned short)src[e];
}

// ---- L3: [gemm blocks] H'(bf16) = dinv*(Xh@W1), B dbuf in LDS, blockDim 128
//          [reg blocks]  4-lane-per-edge CSR count, 512 edges/block ----
template <int NF, int KB>   // 8, 16
__global__ void k_gemm1_reg(const unsigned short* __restrict__ Xh,
                            const unsigned short* __restrict__ Bh,
                            const unsigned short* __restrict__ Bl,
                            unsigned short* __restrict__ H0, int M,
                            const int* __restrict__ cnt,
                            const int* __restrict__ src, const int* __restrict__ dst, int E,
                            const unsigned short* __restrict__ csr,
                            float* __restrict__ regp, int gemmBlocks) {
    if ((int)blockIdx.x >= gemmBlocks) {
        // ---- reg: group of 4 lanes per edge; each lane strides 32 entries ----
        int b = (int)blockIdx.x - gemmBlocks;
        int g = threadIdx.x >> 2;          // 0..31
        int sub = threadIdx.x & 3;
        int base = b * 512;
        int c = 0;
        for (int it = 0; it < 16; it++) {
            int e = base + it * 32 + g;
            if (e < E) {
                int s = src[e];
                unsigned d = (unsigned)dst[e];
                int len = min(cnt[s], CAP);
                const unsigned short* row = csr + (size_t)s * CAP;  // 256B-aligned
                for (int i = sub * 8; i < len; i += 32) {           // 64B-aligned uint4
                    uint4 v = *(const uint4*)(row + i);
                    c += ((v.x & 0xffffu) == d) ? 1 : 0;
                    c += ((v.x >> 16) == d && i + 1 < len) ? 1 : 0;
                    c += ((v.y & 0xffffu) == d && i + 2 < len) ? 1 : 0;
                    c += ((v.y >> 16) == d && i + 3 < len) ? 1 : 0;
                    c += ((v.z & 0xffffu) == d && i + 4 < len) ? 1 : 0;
                    c += ((v.z >> 16) == d && i + 5 < len) ? 1 : 0;
                    c += ((v.w & 0xffffu) == d && i + 6 < len) ? 1 : 0;
                    c += ((v.w >> 16) == d && i + 7 < len) ? 1 : 0;
                }
            }
        }
#pragma unroll
        for (int off = 32; off; off >>= 1) c += __shfl_xor(c, off, 64);
        if ((threadIdx.x & 63) == 0 && c) atomicAdd(regp, (float)c);
        return;
    }
    const int K = KB * 32, N = NF * 16;
    const int CH = NF * 64;                       // 512 uint4 per (hi|lo) per kb
    __shared__ uint4 sB[2][2 * NF * 64];          // 16 KB/slot
    int w = threadIdx.x >> 6, lane = threadIdx.x & 63;
    int m0 = blockIdx.x * 32 + w * 16;
    bool valid = (m0 < M);
    int arow = valid ? (m0 + (lane & 15)) : 0;

    const uint4* GH = (const uint4*)Bh;
    const uint4* GL = (const uint4*)Bl;
    float4v acc[NF] = {};
    const short8* A = (const short8*)(Xh + (size_t)arow * K) + (lane >> 4);
    short8 a = A[0];

#pragma unroll
    for (int c = threadIdx.x; c < CH; c += 128) {
        sB[0][c] = GH[c];
        sB[0][CH + c] = GL[c];
    }
    __syncthreads();

    for (int kb = 0; kb < KB; kb++) {
        int slot = kb & 1;
        if (kb + 1 < KB) {
            const uint4* gh = GH + (kb + 1) * CH;
            const uint4* gl = GL + (kb + 1) * CH;
#pragma unroll
            for (int c = threadIdx.x; c < CH; c += 128) {
                sB[slot ^ 1][c] = gh[c];
                sB[slot ^ 1][CH + c] = gl[c];
            }
        }
        short8 an = (kb + 1 < KB) ? A[(kb + 1) * 4] : a;
        const short8* sb = (const short8*)sB[slot];
#pragma unroll
        for (int f = 0; f < NF; f++) {
            short8 bh = sb[f * 64 + lane];
            short8 bl = sb[CH + f * 64 + lane];
            acc[f] = __builtin_amdgcn_mfma_f32_16x16x32_bf16(a, bh, acc[f], 0, 0, 0);
            acc[f] = __builtin_amdgcn_mfma_f32_16x16x32_bf16(a, bl, acc[f], 0, 0, 0);
        }
        a = an;
        __syncthreads();
    }
    if (!valid) return;
    int row = (lane >> 4) * 4, col = lane & 15;
    float dd[4];
#pragma unroll
    for (int r = 0; r < 4; r++)
        dd[r] = rsqrtf((float)min(cnt[m0 + row + r], CAP) + 1.0f);
#pragma unroll
    for (int f = 0; f < NF; f++)
#pragma unroll
        for (int r = 0; r < 4; r++)
            H0[(size_t)(m0 + row + r) * N + f * 16 + col] = f2bf(acc[f][r] * dd[r]);
}

// ---- L4: 16 waves/block, wave per node: gather AGG1 row -> LDS; wave 0: fused GEMM2 ----
// LDS rows stride 68 words (not 64) so the 16 A-frag ds_read_b128 lanes land 2-way (free).
__global__ __launch_bounds__(1024)
void k_agg1_gemm2(const int* __restrict__ cnt, const unsigned short* __restrict__ csr,
                  const unsigned short* __restrict__ H, const float* __restrict__ b1,
                  const unsigned short* __restrict__ Bh2, const unsigned short* __restrict__ Bl2,
                  unsigned short* __restrict__ LGb, int Nn) {
    __shared__ unsigned rowbuf[16 * 68];   // 16 rows x 128 bf16 (pairs), stride 68 words
    __shared__ float sdd[16];
    int w = threadIdx.x >> 6, lane = threadIdx.x & 63;
    int wid = blockIdx.x * 16 + w;
    if (wid < Nn) {
        int len = min(cnt[wid], CAP);
        const unsigned* H2 = (const unsigned*)H;   // bf16x2 per lane
        unsigned ph = H2[(unsigned)(wid << 6) + lane];
        float accx = __uint_as_float(ph << 16);            // self-loop: + H'[d]
        float accy = __uint_as_float(ph & 0xffff0000u);
        const unsigned short* row = csr + (size_t)wid * CAP;  // 256B-aligned
        int j = 0;
        for (; j + 16 <= len; j += 16) {
            uint4 iv0 = *(const uint4*)(row + j);
            uint4 iv1 = *(const uint4*)(row + j + 8);
            unsigned s[16];
            s[0] = iv0.x & 0xffff; s[1] = iv0.x >> 16; s[2] = iv0.y & 0xffff; s[3] = iv0.y >> 16;
            s[4] = iv0.z & 0xffff; s[5] = iv0.z >> 16; s[6] = iv0.w & 0xffff; s[7] = iv0.w >> 16;
            s[8] = iv1.x & 0xffff; s[9] = iv1.x >> 16; s[10] = iv1.y & 0xffff; s[11] = iv1.y >> 16;
            s[12] = iv1.z & 0xffff; s[13] = iv1.z >> 16; s[14] = iv1.w & 0xffff; s[15] = iv1.w >> 16;
            unsigned p[16];
#pragma unroll
            for (int q = 0; q < 16; q++) p[q] = H2[(s[q] << 6) + lane];
#pragma unroll
            for (int q = 0; q < 16; q++) {
                accx += __uint_as_float(p[q] << 16);
                accy += __uint_as_float(p[q] & 0xffff0000u);
            }
        }
        for (; j + 8 <= len; j += 8) {
            uint4 iv0 = *(const uint4*)(row + j);
            unsigned s[8];
            s[0] = iv0.x & 0xffff; s[1] = iv0.x >> 16; s[2] = iv0.y & 0xffff; s[3] = iv0.y >> 16;
            s[4] = iv0.z & 0xffff; s[5] = iv0.z >> 16; s[6] = iv0.w & 0xffff; s[7] = iv0.w >> 16;
            unsigned p[8];
#pragma unroll
            for (int q = 0; q < 8; q++) p[q] = H2[(s[q] << 6) + lane];
#pragma unroll
            for (int q = 0; q < 8; q++) {
                accx += __uint_as_float(p[q] << 16);
                accy += __uint_as_float(p[q] & 0xffff0000u);
            }
        }
        for (; j < len; j++) {
            unsigned p0 = H2[((unsigned)row[j] << 6) + lane];
            accx += __uint_as_float(p0 << 16);
            accy += __uint_as_float(p0 & 0xffff0000u);
        }
        float dd = rsqrtf((float)len + 1.0f);
        float2 bb = ((const float2*)b1)[lane];
        float vx = dd * accx + bb.x, vy = dd * accy + bb.y;
        vx = vx > 0.f ? vx : 0.f;
        vy = vy > 0.f ? vy : 0.f;
        rowbuf[w * 68 + lane] = (unsigned)f2bf(vx) | ((unsigned)f2bf(vy) << 16);
        if (lane == 0) sdd[w] = dd;
    }
    __syncthreads();
    if (w == 0) {
        // fused GEMM2 for this block's 16 nodes: LG'[m][f] = sdd[m] * (AGG1row[m] @ W2)
        float4v acc2[3] = {};
        const short8* BH = ((const short8*)Bh2) + lane;
        const short8* BL = ((const short8*)Bl2) + lane;
        int m = lane & 15, quad = lane >> 4;
#pragma unroll
        for (int kb = 0; kb < 4; kb++) {
            const unsigned* ap = &rowbuf[m * 68 + kb * 16 + quad * 4];
            short8 a = *reinterpret_cast<const short8*>(ap);
#pragma unroll
            for (int f = 0; f < 3; f++) {
                short8 bh = BH[(kb * 3 + f) * 64];
                short8 bl = BL[(kb * 3 + f) * 64];
                acc2[f] = __builtin_amdgcn_mfma_f32_16x16x32_bf16(a, bh, acc2[f], 0, 0, 0);
                acc2[f] = __builtin_amdgcn_mfma_f32_16x16x32_bf16(a, bl, acc2[f], 0, 0, 0);
            }
        }
        int col = lane & 15, rbase = (lane >> 4) * 4;
#pragma unroll
        for (int f = 0; f < 3; f++)
#pragma unroll
            for (int r = 0; r < 4; r++) {
                int node = rbase + r;
                int g = blockIdx.x * 16 + node;
                if (g < Nn)
                    LGb[(size_t)g * 48 + f * 16 + col] = f2bf(acc2[f][r] * sdd[node]);
            }
    }
}

// ---- L5: pure-sum gather over LG' (bf16, stride 48) + bias + log_softmax ----
__global__ void k_agg2_lsm(const int* __restrict__ cnt, const unsigned short* __restrict__ csr,
                           const unsigned short* __restrict__ LGb, const float* __restrict__ b2,
                           const float* __restrict__ regp, float* __restrict__ out,
                           int Nn, int F) {
    int wid = (int)(blockIdx.x * blockDim.x + threadIdx.x) >> 6;
    int lane = threadIdx.x & 63;
    if (wid >= Nn) return;
    int len = min(cnt[wid], CAP);
    bool act = lane < F;
    float acc = act ? bf2f(LGb[(unsigned)wid * 48 + lane]) : 0.f;   // self-loop
    const unsigned short* row = csr + (size_t)wid * CAP;
    int j = 0;
    for (; j + 8 <= len; j += 8) {
        uint4 idv = *(const uint4*)(row + j);
        unsigned s[8];
        s[0] = idv.x & 0xffff; s[1] = idv.x >> 16; s[2] = idv.y & 0xffff; s[3] = idv.y >> 16;
        s[4] = idv.z & 0xffff; s[5] = idv.z >> 16; s[6] = idv.w & 0xffff; s[7] = idv.w >> 16;
        unsigned short a[8];
#pragma unroll
        for (int q = 0; q < 8; q++) a[q] = act ? LGb[s[q] * 48 + lane] : (unsigned short)0;
#pragma unroll
        for (int q = 0; q < 8; q++) acc += __uint_as_float((unsigned)a[q] << 16);
    }
    for (; j < len; j++) {
        unsigned short a0 = act ? LGb[(unsigned)row[j] * 48 + lane] : (unsigned short)0;
        acc += __uint_as_float((unsigned)a0 << 16);
    }
    float dd = rsqrtf((float)len + 1.0f);
    float v = act ? dd * acc + b2[lane] : -1e30f;
    float m = v;
#pragma unroll
    for (int off = 32; off; off >>= 1) m = fmaxf(m, __shfl_xor(m, off, 64));
    float ex = act ? expf(v - m) : 0.f;
    float ssum = ex;
#pragma unroll
    for (int off = 32; off; off >>= 1) ssum += __shfl_xor(ssum, off, 64);
    if (act) out[(size_t)wid * F + lane] = v - m - logf(ssum);
    if (wid == 0 && lane == 0) out[(size_t)Nn * F] = regp[0];
}

extern "C" void kernel_launch(void* const* d_in, const int* in_sizes, int n_in,
                              void* d_out, int out_size, void* d_ws, size_t ws_size,
                              hipStream_t stream) {
    const float* x  = (const float*)d_in[0];
    const int*   ei = (const int*)d_in[1];
    const float* W1 = (const float*)d_in[2];
    const float* b1 = (const float*)d_in[3];
    const float* W2 = (const float*)d_in[4];
    const float* b2 = (const float*)d_in[5];
    float* out = (float*)d_out;

    const int FH   = in_sizes[3];            // 128
    const int FOUT = in_sizes[5];            // 40
    const int FIN  = in_sizes[2] / FH;       // 512
    const int Nn   = in_sizes[0] / FIN;      // 10000
    const int E    = in_sizes[1] / 2;        // 320000
    const int* src = ei;
    const int* dst = ei + E;

    // ---- workspace layout (all bases 16B-aligned; csr rows 256B-aligned) ----
    int*   cnt  = (int*)d_ws;                                 // Nn
    float* regp = (float*)(cnt + Nn);                         // 16 (1 used)
    unsigned short* csr   = (unsigned short*)(regp + 16);     // Nn*CAP
    unsigned short* Xh    = csr + (size_t)Nn * CAP;           // Nn*FIN
    unsigned short* H0b   = Xh + (size_t)Nn * FIN;            // Nn*FH
    unsigned short* Bh1   = H0b + (size_t)Nn * FH;            // 65536
    unsigned short* Bl1   = Bh1 + 65536;
    unsigned short* Bh2   = Bl1 + 65536;                      // 6144
    unsigned short* Bl2   = Bh2 + 6144;
    unsigned short* LGb   = Bl2 + 6144;                       // Nn*48

    // L1: pack W1/W2 + zero cnt/regp
    int p1B = (16 * 8 * 64) / 256;             // 32
    int p2B = (4 * 3 * 64 + 255) / 256;        // 3
    int zints = Nn + 16;
    int zB = (zints + 255) / 256;              // 40
    k_prep<<<p1B + p2B + zB, 256, 0, stream>>>(W1, Bh1, Bl1, W2, Bh2, Bl2,
                                               cnt, zints, p1B, p2B);

    // L2: conv X co-launched with CSR fill
    int total4 = Nn * FIN / 4;                 // 1.28M
    int convB = (total4 + 255) / 256;          // 5000
    int fillB = (E + 255) / 256;               // 1250
    k_conv_fill<<<convB + fillB, 256, 0, stream>>>(x, Xh, total4, src, dst, E, cnt, csr, convB);

    // L3: gemm1 (B LDS dbuf, dinv epilogue) co-launched with 4-lane reg scan
    int gemmB = (Nn + 31) / 32;                // 313
    int regB  = (E + 511) / 512;               // 625
    k_gemm1_reg<8, 16><<<gemmB + regB, 128, 0, stream>>>(
        Xh, Bh1, Bl1, H0b, Nn, cnt, src, dst, E, csr, regp, gemmB);

    // L4: agg1 (pure sum + relu) with fused GEMM2 -> LG'(bf16, stride 48)
    k_agg1_gemm2<<<(Nn + 15) / 16, 1024, 0, stream>>>(
        cnt, csr, H0b, b1, Bh2, Bl2, LGb, Nn);

    // L5: out = log_softmax(dinv*(sum LG') + b2); out[N*F] = reg
    k_agg2_lsm<<<(Nn * 64 + 255) / 256, 256, 0, stream>>>(
        cnt, csr, LGb, b2, regp, out, Nn, FOUT);
}

// Round 14
// 168.583 us; speedup vs baseline: 1.0119x; 1.0119x over previous
//
#include <hip/hip_runtime.h>
#include <hip/hip_bf16.h>

// Problem: N=10000, E=320000, FIN=512, FH=128, FOUT=40 (derived from in_sizes).
// Padded-CSR pipeline (CAP=128 slots/node), GCN norm factored into GEMM epilogues:
//   out[d] = dinv[d] * ( sum_s H'[s] + H'[d] ),  H' = dinv * (X@W1)   (same layer 2)
//  L0 memset       : zero cnt/regp (40 KB)
//  L1 k_front      : [conv] X->bf16 | [fill] csr[d*CAP + atomicAdd(cnt[d])] = src
//                    | [packW1 hi/lo] | [packW2 hi/lo, 40->48]
//  L2 k_gemm1_reg  : [gemm] H'(bf16) = dinv * (Xh @ W1), B LDS dbuf, M-tile 32
//                    [reg]  4-lane groups count dst[e] in csr-row src[e]
//  L3 k_agg1_gemm2 : 16 waves/block, wave per node: AGG1row = relu(dinv*(sum H') + b1)
//                    -> LDS; wave 0 computes LG'[16][48] = dinv * (AGG1 @ W2) (fused GEMM2)
//  L4 k_agg2_lsm   : out = log_softmax(dinv[d]*(sum LG') + b2); out[N*F] = reg
// reg identity: reg = sum_{(s,d) in E} A[d,s]; CSR-by-dst row s holds srcs of edges
// into s, so A[d,s] = #occurrences of d in row s.

#define CAP 128

typedef __attribute__((ext_vector_type(8))) short short8;   // 8 x bf16 (4 VGPRs)
typedef __attribute__((ext_vector_type(4))) float float4v;  // MFMA C/D

__device__ __forceinline__ unsigned short f2bf(float f) {
    __hip_bfloat16 b = __float2bfloat16(f);
    return *reinterpret_cast<unsigned short*>(&b);
}
__device__ __forceinline__ float bf2f(unsigned short u) {
    __hip_bfloat16 b = *reinterpret_cast<__hip_bfloat16*>(&u);
    return __bfloat162float(b);
}

// ---- L1: conv X->bf16 | padded-CSR fill | pack W1 hi/lo | pack W2 hi/lo ----
__global__ void k_front(const float* __restrict__ x, unsigned short* __restrict__ xh, int total4,
                        const int* __restrict__ src, const int* __restrict__ dst, int E,
                        int* __restrict__ cnt, unsigned short* __restrict__ csr,
                        const float* __restrict__ W1, unsigned short* __restrict__ Bh1,
                        unsigned short* __restrict__ Bl1,
                        const float* __restrict__ W2, unsigned short* __restrict__ Bh2,
                        unsigned short* __restrict__ Bl2,
                        int convB, int fillB, int p1B) {
    int b = blockIdx.x;
    if (b < convB) {
        int i = b * 256 + threadIdx.x;
        if (i < total4) {
            float4 v = ((const float4*)x)[i];
            ushort4 h;
            h.x = f2bf(v.x); h.y = f2bf(v.y); h.z = f2bf(v.z); h.w = f2bf(v.w);
            ((ushort4*)xh)[i] = h;
        }
        return;
    }
    b -= convB;
    if (b < fillB) {
        int e = b * 256 + (int)threadIdx.x;
        if (e >= E) return;
        int d = dst[e];
        int pos = atomicAdd(&cnt[d], 1);
        if (pos < CAP) csr[(size_t)d * CAP + pos] = (unsigned short)src[e];
        return;
    }
    b -= fillB;
    if (b < p1B) {   // pack W1: KB=16, NF=8, N=128
        int t = b * 256 + threadIdx.x;
        int lane = t & 63;
        int f = (t >> 6) % 8;
        int kb = (t >> 6) / 8;
        int kbase = kb * 32 + (lane >> 4) * 8;
        int n = f * 16 + (lane & 15);
        unsigned short hj[8], lj[8];
#pragma unroll
        for (int j = 0; j < 8; j++) {
            float v = W1[(size_t)(kbase + j) * 128 + n];
            unsigned short hb = f2bf(v);
            hj[j] = hb;
            lj[j] = f2bf(v - bf2f(hb));
        }
        ushort4 h0 = {hj[0], hj[1], hj[2], hj[3]}, h1 = {hj[4], hj[5], hj[6], hj[7]};
        ushort4 l0 = {lj[0], lj[1], lj[2], lj[3]}, l1 = {lj[4], lj[5], lj[6], lj[7]};
        ((ushort4*)Bh1)[t * 2] = h0; ((ushort4*)Bh1)[t * 2 + 1] = h1;
        ((ushort4*)Bl1)[t * 2] = l0; ((ushort4*)Bl1)[t * 2 + 1] = l1;
        return;
    }
    b -= p1B;
    {   // pack W2: KB=4, NF=3 (48 padded, real N=40)
        int t = b * 256 + threadIdx.x;
        if (t >= 4 * 3 * 64) return;
        int lane = t & 63;
        int f = (t >> 6) % 3;
        int kb = (t >> 6) / 3;
        int kbase = kb * 32 + (lane >> 4) * 8;
        int n = f * 16 + (lane & 15);
        unsigned short hj[8], lj[8];
#pragma unroll
        for (int j = 0; j < 8; j++) {
            float v = (n < 40) ? W2[(size_t)(kbase + j) * 40 + n] : 0.f;
            unsigned short hb = f2bf(v);
            hj[j] = hb;
            lj[j] = f2bf(v - bf2f(hb));
        }
        ushort4 h0 = {hj[0], hj[1], hj[2], hj[3]}, h1 = {hj[4], hj[5], hj[6], hj[7]};
        ushort4 l0 = {lj[0], lj[1], lj[2], lj[3]}, l1 = {lj[4], lj[5], lj[6], lj[7]};
        ((ushort4*)Bh2)[t * 2] = h0; ((ushort4*)Bh2)[t * 2 + 1] = h1;
        ((ushort4*)Bl2)[t * 2] = l0; ((ushort4*)Bl2)[t * 2 + 1] = l1;
    }
}

// ---- L2: [gemm blocks] H'(bf16) = dinv*(Xh@W1), B dbuf in LDS, blockDim 128
//          [reg blocks]  4-lane-per-edge CSR count, 512 edges/block ----
template <int NF, int KB>   // 8, 16
__global__ void k_gemm1_reg(const unsigned short* __restrict__ Xh,
                            const unsigned short* __restrict__ Bh,
                            const unsigned short* __restrict__ Bl,
                            unsigned short* __restrict__ H0, int M,
                            const int* __restrict__ cnt,
                            const int* __restrict__ src, const int* __restrict__ dst, int E,
                            const unsigned short* __restrict__ csr,
                            float* __restrict__ regp, int gemmBlocks) {
    if ((int)blockIdx.x >= gemmBlocks) {
        // ---- reg: group of 4 lanes per edge; each lane strides 32 entries ----
        int b = (int)blockIdx.x - gemmBlocks;
        int g = threadIdx.x >> 2;          // 0..31
        int sub = threadIdx.x & 3;
        int base = b * 512;
        int c = 0;
        for (int it = 0; it < 16; it++) {
            int e = base + it * 32 + g;
            if (e < E) {
                int s = src[e];
                unsigned d = (unsigned)dst[e];
                int len = min(cnt[s], CAP);
                const unsigned short* row = csr + (size_t)s * CAP;  // 256B-aligned
                for (int i = sub * 8; i < len; i += 32) {           // 64B-aligned uint4
                    uint4 v = *(const uint4*)(row + i);
                    c += ((v.x & 0xffffu) == d) ? 1 : 0;
                    c += ((v.x >> 16) == d && i + 1 < len) ? 1 : 0;
                    c += ((v.y & 0xffffu) == d && i + 2 < len) ? 1 : 0;
                    c += ((v.y >> 16) == d && i + 3 < len) ? 1 : 0;
                    c += ((v.z & 0xffffu) == d && i + 4 < len) ? 1 : 0;
                    c += ((v.z >> 16) == d && i + 5 < len) ? 1 : 0;
                    c += ((v.w & 0xffffu) == d && i + 6 < len) ? 1 : 0;
                    c += ((v.w >> 16) == d && i + 7 < len) ? 1 : 0;
                }
            }
        }
#pragma unroll
        for (int off = 32; off; off >>= 1) c += __shfl_xor(c, off, 64);
        if ((threadIdx.x & 63) == 0 && c) atomicAdd(regp, (float)c);
        return;
    }
    const int K = KB * 32, N = NF * 16;
    const int CH = NF * 64;                       // 512 uint4 per (hi|lo) per kb
    __shared__ uint4 sB[2][2 * NF * 64];          // 16 KB/slot
    int w = threadIdx.x >> 6, lane = threadIdx.x & 63;
    int m0 = blockIdx.x * 32 + w * 16;
    bool valid = (m0 < M);
    int arow = valid ? (m0 + (lane & 15)) : 0;

    const uint4* GH = (const uint4*)Bh;
    const uint4* GL = (const uint4*)Bl;
    float4v acc[NF] = {};
    const short8* A = (const short8*)(Xh + (size_t)arow * K) + (lane >> 4);
    short8 a = A[0];

#pragma unroll
    for (int c = threadIdx.x; c < CH; c += 128) {
        sB[0][c] = GH[c];
        sB[0][CH + c] = GL[c];
    }
    __syncthreads();

    for (int kb = 0; kb < KB; kb++) {
        int slot = kb & 1;
        if (kb + 1 < KB) {
            const uint4* gh = GH + (kb + 1) * CH;
            const uint4* gl = GL + (kb + 1) * CH;
#pragma unroll
            for (int c = threadIdx.x; c < CH; c += 128) {
                sB[slot ^ 1][c] = gh[c];
                sB[slot ^ 1][CH + c] = gl[c];
            }
        }
        short8 an = (kb + 1 < KB) ? A[(kb + 1) * 4] : a;
        const short8* sb = (const short8*)sB[slot];
#pragma unroll
        for (int f = 0; f < NF; f++) {
            short8 bh = sb[f * 64 + lane];
            short8 bl = sb[CH + f * 64 + lane];
            acc[f] = __builtin_amdgcn_mfma_f32_16x16x32_bf16(a, bh, acc[f], 0, 0, 0);
            acc[f] = __builtin_amdgcn_mfma_f32_16x16x32_bf16(a, bl, acc[f], 0, 0, 0);
        }
        a = an;
        __syncthreads();
    }
    if (!valid) return;
    int row = (lane >> 4) * 4, col = lane & 15;
    float dd[4];
#pragma unroll
    for (int r = 0; r < 4; r++)
        dd[r] = rsqrtf((float)min(cnt[m0 + row + r], CAP) + 1.0f);
#pragma unroll
    for (int f = 0; f < NF; f++)
#pragma unroll
        for (int r = 0; r < 4; r++)
            H0[(size_t)(m0 + row + r) * N + f * 16 + col] = f2bf(acc[f][r] * dd[r]);
}

// ---- L3: 16 waves/block, wave per node: gather AGG1 row -> LDS; wave 0: fused GEMM2 ----
// 4 independent accumulator pairs break the serial FP-add chain (16->4 deps/iter).
__global__ __launch_bounds__(1024)
void k_agg1_gemm2(const int* __restrict__ cnt, const unsigned short* __restrict__ csr,
                  const unsigned short* __restrict__ H, const float* __restrict__ b1,
                  const unsigned short* __restrict__ Bh2, const unsigned short* __restrict__ Bl2,
                  unsigned short* __restrict__ LGb, int Nn) {
    __shared__ unsigned rowbuf[16 * 68];   // 16 rows x 128 bf16 (pairs), stride 68 words
    __shared__ float sdd[16];
    int w = threadIdx.x >> 6, lane = threadIdx.x & 63;
    int wid = blockIdx.x * 16 + w;
    if (wid < Nn) {
        int len = min(cnt[wid], CAP);
        const unsigned* H2 = (const unsigned*)H;   // bf16x2 per lane
        unsigned ph = H2[(unsigned)(wid << 6) + lane];
        float ax0 = __uint_as_float(ph << 16), ax1 = 0.f, ax2 = 0.f, ax3 = 0.f;
        float ay0 = __uint_as_float(ph & 0xffff0000u), ay1 = 0.f, ay2 = 0.f, ay3 = 0.f;
        const unsigned short* row = csr + (size_t)wid * CAP;  // 256B-aligned
        int j = 0;
        for (; j + 16 <= len; j += 16) {
            uint4 iv0 = *(const uint4*)(row + j);
            uint4 iv1 = *(const uint4*)(row + j + 8);
            unsigned s[16];
            s[0] = iv0.x & 0xffff; s[1] = iv0.x >> 16; s[2] = iv0.y & 0xffff; s[3] = iv0.y >> 16;
            s[4] = iv0.z & 0xffff; s[5] = iv0.z >> 16; s[6] = iv0.w & 0xffff; s[7] = iv0.w >> 16;
            s[8] = iv1.x & 0xffff; s[9] = iv1.x >> 16; s[10] = iv1.y & 0xffff; s[11] = iv1.y >> 16;
            s[12] = iv1.z & 0xffff; s[13] = iv1.z >> 16; s[14] = iv1.w & 0xffff; s[15] = iv1.w >> 16;
            unsigned p[16];
#pragma unroll
            for (int q = 0; q < 16; q++) p[q] = H2[(s[q] << 6) + lane];
#pragma unroll
            for (int q = 0; q < 16; q += 4) {
                ax0 += __uint_as_float(p[q] << 16);
                ax1 += __uint_as_float(p[q + 1] << 16);
                ax2 += __uint_as_float(p[q + 2] << 16);
                ax3 += __uint_as_float(p[q + 3] << 16);
                ay0 += __uint_as_float(p[q] & 0xffff0000u);
                ay1 += __uint_as_float(p[q + 1] & 0xffff0000u);
                ay2 += __uint_as_float(p[q + 2] & 0xffff0000u);
                ay3 += __uint_as_float(p[q + 3] & 0xffff0000u);
            }
        }
        for (; j + 8 <= len; j += 8) {
            uint4 iv0 = *(const uint4*)(row + j);
            unsigned s[8];
            s[0] = iv0.x & 0xffff; s[1] = iv0.x >> 16; s[2] = iv0.y & 0xffff; s[3] = iv0.y >> 16;
            s[4] = iv0.z & 0xffff; s[5] = iv0.z >> 16; s[6] = iv0.w & 0xffff; s[7] = iv0.w >> 16;
            unsigned p[8];
#pragma unroll
            for (int q = 0; q < 8; q++) p[q] = H2[(s[q] << 6) + lane];
#pragma unroll
            for (int q = 0; q < 8; q += 4) {
                ax0 += __uint_as_float(p[q] << 16);
                ax1 += __uint_as_float(p[q + 1] << 16);
                ax2 += __uint_as_float(p[q + 2] << 16);
                ax3 += __uint_as_float(p[q + 3] << 16);
                ay0 += __uint_as_float(p[q] & 0xffff0000u);
                ay1 += __uint_as_float(p[q + 1] & 0xffff0000u);
                ay2 += __uint_as_float(p[q + 2] & 0xffff0000u);
                ay3 += __uint_as_float(p[q + 3] & 0xffff0000u);
            }
        }
        for (; j < len; j++) {
            unsigned p0 = H2[((unsigned)row[j] << 6) + lane];
            ax0 += __uint_as_float(p0 << 16);
            ay0 += __uint_as_float(p0 & 0xffff0000u);
        }
        float accx = (ax0 + ax1) + (ax2 + ax3);
        float accy = (ay0 + ay1) + (ay2 + ay3);
        float dd = rsqrtf((float)len + 1.0f);
        float2 bb = ((const float2*)b1)[lane];
        float vx = dd * accx + bb.x, vy = dd * accy + bb.y;
        vx = vx > 0.f ? vx : 0.f;
        vy = vy > 0.f ? vy : 0.f;
        rowbuf[w * 68 + lane] = (unsigned)f2bf(vx) | ((unsigned)f2bf(vy) << 16);
        if (lane == 0) sdd[w] = dd;
    }
    __syncthreads();
    if (w == 0) {
        // fused GEMM2 for this block's 16 nodes: LG'[m][f] = sdd[m] * (AGG1row[m] @ W2)
        float4v acc2[3] = {};
        const short8* BH = ((const short8*)Bh2) + lane;
        const short8* BL = ((const short8*)Bl2) + lane;
        int m = lane & 15, quad = lane >> 4;
#pragma unroll
        for (int kb = 0; kb < 4; kb++) {
            const unsigned* ap = &rowbuf[m * 68 + kb * 16 + quad * 4];
            short8 a = *reinterpret_cast<const short8*>(ap);
#pragma unroll
            for (int f = 0; f < 3; f++) {
                short8 bh = BH[(kb * 3 + f) * 64];
                short8 bl = BL[(kb * 3 + f) * 64];
                acc2[f] = __builtin_amdgcn_mfma_f32_16x16x32_bf16(a, bh, acc2[f], 0, 0, 0);
                acc2[f] = __builtin_amdgcn_mfma_f32_16x16x32_bf16(a, bl, acc2[f], 0, 0, 0);
            }
        }
        int col = lane & 15, rbase = (lane >> 4) * 4;
#pragma unroll
        for (int f = 0; f < 3; f++)
#pragma unroll
            for (int r = 0; r < 4; r++) {
                int node = rbase + r;
                int g = blockIdx.x * 16 + node;
                if (g < Nn)
                    LGb[(size_t)g * 48 + f * 16 + col] = f2bf(acc2[f][r] * sdd[node]);
            }
    }
}

// ---- L4: pure-sum gather over LG' (bf16, stride 48) + bias + log_softmax ----
__global__ void k_agg2_lsm(const int* __restrict__ cnt, const unsigned short* __restrict__ csr,
                           const unsigned short* __restrict__ LGb, const float* __restrict__ b2,
                           const float* __restrict__ regp, float* __restrict__ out,
                           int Nn, int F) {
    int wid = (int)(blockIdx.x * blockDim.x + threadIdx.x) >> 6;
    int lane = threadIdx.x & 63;
    if (wid >= Nn) return;
    int len = min(cnt[wid], CAP);
    bool act = lane < F;
    float a0c = act ? bf2f(LGb[(unsigned)wid * 48 + lane]) : 0.f;   // self-loop
    float a1c = 0.f, a2c = 0.f, a3c = 0.f;
    const unsigned short* row = csr + (size_t)wid * CAP;
    int j = 0;
    for (; j + 8 <= len; j += 8) {
        uint4 idv = *(const uint4*)(row + j);
        unsigned s[8];
        s[0] = idv.x & 0xffff; s[1] = idv.x >> 16; s[2] = idv.y & 0xffff; s[3] = idv.y >> 16;
        s[4] = idv.z & 0xffff; s[5] = idv.z >> 16; s[6] = idv.w & 0xffff; s[7] = idv.w >> 16;
        unsigned short a[8];
#pragma unroll
        for (int q = 0; q < 8; q++) a[q] = act ? LGb[s[q] * 48 + lane] : (unsigned short)0;
        a0c += __uint_as_float((unsigned)a[0] << 16);
        a1c += __uint_as_float((unsigned)a[1] << 16);
        a2c += __uint_as_float((unsigned)a[2] << 16);
        a3c += __uint_as_float((unsigned)a[3] << 16);
        a0c += __uint_as_float((unsigned)a[4] << 16);
        a1c += __uint_as_float((unsigned)a[5] << 16);
        a2c += __uint_as_float((unsigned)a[6] << 16);
        a3c += __uint_as_float((unsigned)a[7] << 16);
    }
    for (; j < len; j++) {
        unsigned short a0 = act ? LGb[(unsigned)row[j] * 48 + lane] : (unsigned short)0;
        a0c += __uint_as_float((unsigned)a0 << 16);
    }
    float acc = (a0c + a1c) + (a2c + a3c);
    float dd = rsqrtf((float)len + 1.0f);
    float v = act ? dd * acc + b2[lane] : -1e30f;
    float m = v;
#pragma unroll
    for (int off = 32; off; off >>= 1) m = fmaxf(m, __shfl_xor(m, off, 64));
    float ex = act ? expf(v - m) : 0.f;
    float ssum = ex;
#pragma unroll
    for (int off = 32; off; off >>= 1) ssum += __shfl_xor(ssum, off, 64);
    if (act) out[(size_t)wid * F + lane] = v - m - logf(ssum);
    if (wid == 0 && lane == 0) out[(size_t)Nn * F] = regp[0];
}

extern "C" void kernel_launch(void* const* d_in, const int* in_sizes, int n_in,
                              void* d_out, int out_size, void* d_ws, size_t ws_size,
                              hipStream_t stream) {
    const float* x  = (const float*)d_in[0];
    const int*   ei = (const int*)d_in[1];
    const float* W1 = (const float*)d_in[2];
    const float* b1 = (const float*)d_in[3];
    const float* W2 = (const float*)d_in[4];
    const float* b2 = (const float*)d_in[5];
    float* out = (float*)d_out;

    const int FH   = in_sizes[3];            // 128
    const int FOUT = in_sizes[5];            // 40
    const int FIN  = in_sizes[2] / FH;       // 512
    const int Nn   = in_sizes[0] / FIN;      // 10000
    const int E    = in_sizes[1] / 2;        // 320000
    const int* src = ei;
    const int* dst = ei + E;

    // ---- workspace layout (all bases 16B-aligned; csr rows 256B-aligned) ----
    int*   cnt  = (int*)d_ws;                                 // Nn
    float* regp = (float*)(cnt + Nn);                         // 16 (1 used)
    unsigned short* csr   = (unsigned short*)(regp + 16);     // Nn*CAP
    unsigned short* Xh    = csr + (size_t)Nn * CAP;           // Nn*FIN
    unsigned short* H0b   = Xh + (size_t)Nn * FIN;            // Nn*FH
    unsigned short* Bh1   = H0b + (size_t)Nn * FH;            // 65536
    unsigned short* Bl1   = Bh1 + 65536;
    unsigned short* Bh2   = Bl1 + 65536;                      // 6144
    unsigned short* Bl2   = Bh2 + 6144;
    unsigned short* LGb   = Bl2 + 6144;                       // Nn*48

    // L0: zero cnt + regp (40 KB)
    hipMemsetAsync(d_ws, 0, ((size_t)Nn + 16) * 4, stream);

    // L1: conv X | CSR fill | pack W1 | pack W2 (one launch)
    int total4 = Nn * FIN / 4;                 // 1.28M
    int convB = (total4 + 255) / 256;          // 5000
    int fillB = (E + 255) / 256;               // 1250
    int p1B = (16 * 8 * 64) / 256;             // 32
    int p2B = (4 * 3 * 64 + 255) / 256;        // 3
    k_front<<<convB + fillB + p1B + p2B, 256, 0, stream>>>(
        x, Xh, total4, src, dst, E, cnt, csr, W1, Bh1, Bl1, W2, Bh2, Bl2,
        convB, fillB, p1B);

    // L2: gemm1 (B LDS dbuf, dinv epilogue) co-launched with 4-lane reg scan
    int gemmB = (Nn + 31) / 32;                // 313
    int regB  = (E + 511) / 512;               // 625
    k_gemm1_reg<8, 16><<<gemmB + regB, 128, 0, stream>>>(
        Xh, Bh1, Bl1, H0b, Nn, cnt, src, dst, E, csr, regp, gemmB);

    // L3: agg1 (pure sum + relu) with fused GEMM2 -> LG'(bf16, stride 48)
    k_agg1_gemm2<<<(Nn + 15) / 16, 1024, 0, stream>>>(
        cnt, csr, H0b, b1, Bh2, Bl2, LGb, Nn);

    // L4: out = log_softmax(dinv*(sum LG') + b2); out[N*F] = reg
    k_agg2_lsm<<<(Nn * 64 + 255) / 256, 256, 0, stream>>>(
        cnt, csr, LGb, b2, regp, out, Nn, FOUT);
}